// Round 1
// baseline (2856.436 us; speedup 1.0000x reference)
//
#include <hip/hip_runtime.h>
#include <math.h>

#define SDIM 4096
#define DIN  1024
#define DOUT 64
#define BB   4

// ---------------------------------------------------------------------------
// Projection: out[row][o] = sum_i x[row][i] * W[o][i]   (torch Linear, x@W^T)
// M = B*S = 16384 rows, N = 64 per weight matrix, K = 1024.
// grid = (M/64, 3)  block = 256.  blockIdx.y selects Wq/Wk/Wv and the output
// slice inside the workspace (qkv = [3][M][64] f32).
// Tiled register GEMM: 64x64 output tile, BK=32, 4x4 micro-tile per thread.
// ---------------------------------------------------------------------------
__global__ __launch_bounds__(256) void proj_kernel(
    const float* __restrict__ x,
    const float* __restrict__ Wq,
    const float* __restrict__ Wk,
    const float* __restrict__ Wv,
    float* __restrict__ qkv) {
  const int M = BB * SDIM;
  const float* W = (blockIdx.y == 0) ? Wq : (blockIdx.y == 1) ? Wk : Wv;
  float* out = qkv + (size_t)blockIdx.y * M * DOUT;
  const int row0 = blockIdx.x * 64;

  // stride 36 floats: 144 B rows -> 16B-aligned float4 reads, breaks pow2 banks
  __shared__ float Xs[64][36];
  __shared__ float Ws[64][36];

  const int t  = threadIdx.x;
  const int tx = t & 15;        // col group
  const int ty = t >> 4;        // row group

  float acc[4][4] = {};

  for (int k0 = 0; k0 < DIN; k0 += 32) {
    // Stage 64x32 of X and W. 2048 floats each; 8 floats (2 x float4)/thread.
    {
      const int r = t >> 2;
      const int c = (t & 3) * 8;
      const float* xp = x + (size_t)(row0 + r) * DIN + k0 + c;
      float4 a0 = *(const float4*)(xp);
      float4 a1 = *(const float4*)(xp + 4);
      *(float4*)&Xs[r][c]     = a0;
      *(float4*)&Xs[r][c + 4] = a1;
      const float* wp = W + (size_t)r * DIN + k0 + c;
      float4 b0 = *(const float4*)(wp);
      float4 b1 = *(const float4*)(wp + 4);
      *(float4*)&Ws[r][c]     = b0;
      *(float4*)&Ws[r][c + 4] = b1;
    }
    __syncthreads();

#pragma unroll
    for (int kk = 0; kk < 32; kk += 4) {
      float4 a[4], b[4];
#pragma unroll
      for (int i = 0; i < 4; i++) a[i] = *(const float4*)&Xs[ty * 4 + i][kk];
#pragma unroll
      for (int j = 0; j < 4; j++) b[j] = *(const float4*)&Ws[tx * 4 + j][kk];
#pragma unroll
      for (int i = 0; i < 4; i++)
#pragma unroll
        for (int j = 0; j < 4; j++)
          acc[i][j] += a[i].x * b[j].x + a[i].y * b[j].y +
                       a[i].z * b[j].z + a[i].w * b[j].w;
    }
    __syncthreads();
  }

#pragma unroll
  for (int i = 0; i < 4; i++)
#pragma unroll
    for (int j = 0; j < 4; j++)
      out[(size_t)(row0 + ty * 4 + i) * DOUT + (tx * 4 + j)] = acc[i][j];
}

// ---------------------------------------------------------------------------
// Flash-style causal attention, f32, one wave per query row.
// lane = head-dim index (DOUT == 64 == wave width).
// Online softmax state (m, lsum) replicated across lanes (identical values).
// grid = (S/4, B), block = 256 (4 waves -> 4 consecutive q rows).
// Batch on grid.y (slow dim) so co-resident blocks share one batch's K/V
// (2 MB) inside per-XCD L2.
// ---------------------------------------------------------------------------
__global__ __launch_bounds__(256) void attn_kernel(
    const float* __restrict__ qkv, float* __restrict__ out) {
  const int M = BB * SDIM;
  const float* qs = qkv;
  const float* ks = qkv + (size_t)M * DOUT;
  const float* vs = qkv + (size_t)2 * M * DOUT;

  const int b    = blockIdx.y;
  const int wave = threadIdx.x >> 6;
  const int lane = threadIdx.x & 63;
  const int r    = blockIdx.x * 4 + wave;   // query row within batch

  const float* qb = qs + (size_t)b * SDIM * DOUT;
  const float* kb = ks + (size_t)b * SDIM * DOUT;
  const float* vb = vs + (size_t)b * SDIM * DOUT;

  const float qv = qb[(size_t)r * DOUT + lane];
  const float scale = 0.125f;   // 1/sqrt(64)

  float m = -INFINITY, lsum = 0.f, o = 0.f;

  const int nj = r + 1;   // causal: keys 0..r inclusive
  int j = 0;

  for (; j + 4 <= nj; j += 4) {
    float s0 = qv * kb[(size_t)(j + 0) * DOUT + lane];
    float s1 = qv * kb[(size_t)(j + 1) * DOUT + lane];
    float s2 = qv * kb[(size_t)(j + 2) * DOUT + lane];
    float s3 = qv * kb[(size_t)(j + 3) * DOUT + lane];
#pragma unroll
    for (int off = 1; off < 64; off <<= 1) {
      s0 += __shfl_xor(s0, off);
      s1 += __shfl_xor(s1, off);
      s2 += __shfl_xor(s2, off);
      s3 += __shfl_xor(s3, off);
    }
    const float v0 = vb[(size_t)(j + 0) * DOUT + lane];
    const float v1 = vb[(size_t)(j + 1) * DOUT + lane];
    const float v2 = vb[(size_t)(j + 2) * DOUT + lane];
    const float v3 = vb[(size_t)(j + 3) * DOUT + lane];
    s0 *= scale; s1 *= scale; s2 *= scale; s3 *= scale;

    // block online-softmax update (exact)
    const float tm   = fmaxf(fmaxf(s0, s1), fmaxf(s2, s3));
    const float newm = fmaxf(m, tm);
    const float alpha = __expf(m - newm);   // m=-inf -> alpha=0 on first tile
    const float p0 = __expf(s0 - newm);
    const float p1 = __expf(s1 - newm);
    const float p2 = __expf(s2 - newm);
    const float p3 = __expf(s3 - newm);
    lsum = lsum * alpha + ((p0 + p1) + (p2 + p3));
    o    = o * alpha + (p0 * v0 + p1 * v1) + (p2 * v2 + p3 * v3);
    m = newm;
  }
  for (; j < nj; ++j) {
    float s = qv * kb[(size_t)j * DOUT + lane];
#pragma unroll
    for (int off = 1; off < 64; off <<= 1) s += __shfl_xor(s, off);
    s *= scale;
    const float v0 = vb[(size_t)j * DOUT + lane];
    const float newm  = fmaxf(m, s);
    const float alpha = __expf(m - newm);
    const float p     = __expf(s - newm);
    lsum = lsum * alpha + p;
    o    = o * alpha + p * v0;
    m = newm;
  }

  out[((size_t)b * SDIM + r) * DOUT + lane] = o / lsum;
}

extern "C" void kernel_launch(void* const* d_in, const int* in_sizes, int n_in,
                              void* d_out, int out_size, void* d_ws, size_t ws_size,
                              hipStream_t stream) {
  const float* x  = (const float*)d_in[0];
  const float* Wq = (const float*)d_in[1];
  const float* Wk = (const float*)d_in[2];
  const float* Wv = (const float*)d_in[3];
  float* out = (float*)d_out;
  float* qkv = (float*)d_ws;   // [3][B*S][64] f32 = 12 MB, fully overwritten

  dim3 gp(BB * SDIM / 64, 3);
  proj_kernel<<<gp, dim3(256), 0, stream>>>(x, Wq, Wk, Wv, qkv);

  dim3 ga(SDIM / 4, BB);
  attn_kernel<<<ga, dim3(256), 0, stream>>>(qkv, out);
}

// Round 2
// 434.698 us; speedup vs baseline: 6.5711x; 6.5711x over previous
//
#include <hip/hip_runtime.h>
#include <math.h>

#define SDIM 4096
#define DIN  1024
#define DOUT 64
#define BB   4

typedef __attribute__((ext_vector_type(8))) short short8;   // 8 x bf16
typedef __attribute__((ext_vector_type(4))) float floatx4;

// round-to-nearest-even f32 -> bf16 bit pattern
static __device__ __forceinline__ unsigned short f2bf(float f) {
  union { float f; unsigned int u; } v; v.f = f;
  unsigned int r = v.u + 0x7fffu + ((v.u >> 16) & 1u);
  return (unsigned short)(r >> 16);
}

// ---------------------------------------------------------------------------
// Projection: qkv_bf16[y][row][o] = bf16( (x @ W_y^T) * (y==0 ? 0.125 : 1) )
// M=16384 rows, N=64, K=1024.  f32 vector-ALU GEMM (near memory bound on the
// 64 MB x read); only the store changed to bf16 + fold the 1/sqrt(64) into q.
// ---------------------------------------------------------------------------
__global__ __launch_bounds__(256) void proj_kernel(
    const float* __restrict__ x,
    const float* __restrict__ Wq,
    const float* __restrict__ Wk,
    const float* __restrict__ Wv,
    unsigned short* __restrict__ qkv) {
  const int M = BB * SDIM;
  const float* W = (blockIdx.y == 0) ? Wq : (blockIdx.y == 1) ? Wk : Wv;
  unsigned short* out = qkv + (size_t)blockIdx.y * M * DOUT;
  const float oscale = (blockIdx.y == 0) ? 0.125f : 1.0f;
  const int row0 = blockIdx.x * 64;

  __shared__ float Xs[64][36];
  __shared__ float Ws[64][36];

  const int t  = threadIdx.x;
  const int tx = t & 15;
  const int ty = t >> 4;

  float acc[4][4] = {};

  for (int k0 = 0; k0 < DIN; k0 += 32) {
    {
      const int r = t >> 2;
      const int c = (t & 3) * 8;
      const float* xp = x + (size_t)(row0 + r) * DIN + k0 + c;
      *(float4*)&Xs[r][c]     = *(const float4*)(xp);
      *(float4*)&Xs[r][c + 4] = *(const float4*)(xp + 4);
      const float* wp = W + (size_t)r * DIN + k0 + c;
      *(float4*)&Ws[r][c]     = *(const float4*)(wp);
      *(float4*)&Ws[r][c + 4] = *(const float4*)(wp + 4);
    }
    __syncthreads();

#pragma unroll
    for (int kk = 0; kk < 32; kk += 4) {
      float4 a[4], b[4];
#pragma unroll
      for (int i = 0; i < 4; i++) a[i] = *(const float4*)&Xs[ty * 4 + i][kk];
#pragma unroll
      for (int j = 0; j < 4; j++) b[j] = *(const float4*)&Ws[tx * 4 + j][kk];
#pragma unroll
      for (int i = 0; i < 4; i++)
#pragma unroll
        for (int j = 0; j < 4; j++)
          acc[i][j] += a[i].x * b[j].x + a[i].y * b[j].y +
                       a[i].z * b[j].z + a[i].w * b[j].w;
    }
    __syncthreads();
  }

#pragma unroll
  for (int i = 0; i < 4; i++) {
    ushort4 u;
    u.x = f2bf(acc[i][0] * oscale);
    u.y = f2bf(acc[i][1] * oscale);
    u.z = f2bf(acc[i][2] * oscale);
    u.w = f2bf(acc[i][3] * oscale);
    *(ushort4*)&out[(size_t)(row0 + ty * 4 + i) * DOUT + tx * 4] = u;
  }
}

// ---------------------------------------------------------------------------
// Flash attention, bf16 MFMA (16x16x32), f32 accumulation.
// grid = (S/64, B), block = 256 (4 waves). Wave w owns query rows
// q0+16w .. q0+16w+15. Per 64-key tile:
//   stage K[64][64] and V^T[64][64] in LDS (stride 72 shorts = 144 B,
//   16B-aligned rows, 2-way-only bank aliasing),
//   S = Q K^T (8 MFMA), online softmax on C-layout frags
//   (row = quad*4+reg, col = lane&15; shuffle masks 1/2/4/8 stay in-quad),
//   P -> LDS (C-layout -> A-layout), O += P V (8 MFMA).
// ---------------------------------------------------------------------------
__global__ __launch_bounds__(256) void attn_kernel(
    const unsigned short* __restrict__ qkv, float* __restrict__ out) {
  const int M = BB * SDIM;
  const unsigned short* qs = qkv;
  const unsigned short* ks = qkv + (size_t)M * DOUT;
  const unsigned short* vs = qkv + (size_t)2 * M * DOUT;

  const int b  = blockIdx.y;
  const int qt = blockIdx.x;
  const int q0 = qt * 64;

  __shared__ __align__(16) short Kl[64 * 72];
  __shared__ __align__(16) short Vt[64 * 72];
  __shared__ __align__(16) short Pl[64 * 72];

  const int tid  = threadIdx.x;
  const int wave = tid >> 6;
  const int lane = tid & 63;
  const int quad = lane >> 4;
  const int l16  = lane & 15;

  // Q fragments (A-operand): row m = l16 of this wave's 16-row block,
  // k = kstep*32 + quad*8 + j. Loaded once, held in registers.
  const unsigned short* qrow =
      qs + (size_t)(b * SDIM + q0 + wave * 16 + l16) * DOUT;
  const short8 aq0 = *(const short8*)(qrow + quad * 8);
  const short8 aq1 = *(const short8*)(qrow + 32 + quad * 8);

  floatx4 o[4] = {floatx4{0,0,0,0}, floatx4{0,0,0,0},
                  floatx4{0,0,0,0}, floatx4{0,0,0,0}};
  float m[4]  = {-INFINITY, -INFINITY, -INFINITY, -INFINITY};
  float lw[4] = {0.f, 0.f, 0.f, 0.f};

  // staging coordinates: thread handles 32B (16 bf16) of one row
  const int sr = tid >> 2;
  const int sc = (tid & 3) * 16;

  for (int kt = 0; kt <= qt; ++kt) {
    const int k0 = kt * 64;
    __syncthreads();   // previous tile's Vt/Pl reads complete before overwrite

    // stage K tile: [key][d], row stride 72
    const unsigned short* kg = ks + (size_t)(b * SDIM + k0 + sr) * DOUT + sc;
    *(short8*)&Kl[sr * 72 + sc]     = *(const short8*)kg;
    *(short8*)&Kl[sr * 72 + sc + 8] = *(const short8*)(kg + 8);

    // stage V transposed: Vt[d][key], row stride 72
    const unsigned short* vg = vs + (size_t)(b * SDIM + k0 + sr) * DOUT + sc;
    short8 v0 = *(const short8*)vg;
    short8 v1 = *(const short8*)(vg + 8);
#pragma unroll
    for (int j = 0; j < 8; j++) {
      Vt[(sc + j) * 72 + sr]     = v0[j];
      Vt[(sc + 8 + j) * 72 + sr] = v1[j];
    }
    __syncthreads();

    // ---- S = Q K^T ----
    floatx4 sa[4] = {floatx4{0,0,0,0}, floatx4{0,0,0,0},
                     floatx4{0,0,0,0}, floatx4{0,0,0,0}};
#pragma unroll
    for (int f = 0; f < 4; f++) {
      const short8 bk0 = *(const short8*)&Kl[(f * 16 + l16) * 72 + quad * 8];
      const short8 bk1 = *(const short8*)&Kl[(f * 16 + l16) * 72 + 32 + quad * 8];
      sa[f] = __builtin_amdgcn_mfma_f32_16x16x32_bf16(aq0, bk0, sa[f], 0, 0, 0);
      sa[f] = __builtin_amdgcn_mfma_f32_16x16x32_bf16(aq1, bk1, sa[f], 0, 0, 0);
    }

    // causal mask (only the diagonal tile needs it)
    if (kt == qt) {
#pragma unroll
      for (int f = 0; f < 4; f++) {
        const int key = k0 + f * 16 + l16;
#pragma unroll
        for (int r = 0; r < 4; r++) {
          const int qr = q0 + wave * 16 + quad * 4 + r;
          if (key > qr) sa[f][r] = -INFINITY;
        }
      }
    }

    // ---- online softmax (per local row r = quad*4 + reg) ----
    float mx[4], al[4], rs[4];
#pragma unroll
    for (int r = 0; r < 4; r++)
      mx[r] = fmaxf(fmaxf(sa[0][r], sa[1][r]), fmaxf(sa[2][r], sa[3][r]));
#pragma unroll
    for (int off = 1; off < 16; off <<= 1)
#pragma unroll
      for (int r = 0; r < 4; r++)
        mx[r] = fmaxf(mx[r], __shfl_xor(mx[r], off));
#pragma unroll
    for (int r = 0; r < 4; r++) {
      const float nm = fmaxf(m[r], mx[r]);
      al[r] = __expf(m[r] - nm);
      m[r]  = nm;
    }
#pragma unroll
    for (int f = 0; f < 4; f++)
#pragma unroll
      for (int r = 0; r < 4; r++)
        sa[f][r] = __expf(sa[f][r] - m[r]);
#pragma unroll
    for (int r = 0; r < 4; r++)
      rs[r] = (sa[0][r] + sa[1][r]) + (sa[2][r] + sa[3][r]);
#pragma unroll
    for (int off = 1; off < 16; off <<= 1)
#pragma unroll
      for (int r = 0; r < 4; r++)
        rs[r] += __shfl_xor(rs[r], off);
#pragma unroll
    for (int r = 0; r < 4; r++) lw[r] = lw[r] * al[r] + rs[r];
#pragma unroll
    for (int f = 0; f < 4; f++)
#pragma unroll
      for (int r = 0; r < 4; r++) o[f][r] *= al[r];

    // ---- P -> LDS (C-layout -> A-layout) ----
#pragma unroll
    for (int f = 0; f < 4; f++)
#pragma unroll
      for (int r = 0; r < 4; r++)
        Pl[(wave * 16 + quad * 4 + r) * 72 + f * 16 + l16] =
            (short)f2bf(sa[f][r]);
    __syncthreads();

    // ---- O += P V ----
    const short8 ap0 = *(const short8*)&Pl[(wave * 16 + l16) * 72 + quad * 8];
    const short8 ap1 = *(const short8*)&Pl[(wave * 16 + l16) * 72 + 32 + quad * 8];
#pragma unroll
    for (int f = 0; f < 4; f++) {
      const short8 bv0 = *(const short8*)&Vt[(f * 16 + l16) * 72 + quad * 8];
      const short8 bv1 = *(const short8*)&Vt[(f * 16 + l16) * 72 + 32 + quad * 8];
      o[f] = __builtin_amdgcn_mfma_f32_16x16x32_bf16(ap0, bv0, o[f], 0, 0, 0);
      o[f] = __builtin_amdgcn_mfma_f32_16x16x32_bf16(ap1, bv1, o[f], 0, 0, 0);
    }
  }

  // epilogue: out[row][dim] = o / l   (C-layout: row=quad*4+r, dim=f*16+l16)
  float inv[4];
#pragma unroll
  for (int r = 0; r < 4; r++) inv[r] = 1.0f / lw[r];
#pragma unroll
  for (int f = 0; f < 4; f++)
#pragma unroll
    for (int r = 0; r < 4; r++)
      out[((size_t)(b * SDIM + q0 + wave * 16 + quad * 4 + r)) * DOUT +
          f * 16 + l16] = o[f][r] * inv[r];
}

extern "C" void kernel_launch(void* const* d_in, const int* in_sizes, int n_in,
                              void* d_out, int out_size, void* d_ws, size_t ws_size,
                              hipStream_t stream) {
  const float* x  = (const float*)d_in[0];
  const float* Wq = (const float*)d_in[1];
  const float* Wk = (const float*)d_in[2];
  const float* Wv = (const float*)d_in[3];
  float* out = (float*)d_out;
  unsigned short* qkv = (unsigned short*)d_ws;  // [3][B*S][64] bf16 = 6 MB

  dim3 gp(BB * SDIM / 64, 3);
  proj_kernel<<<gp, dim3(256), 0, stream>>>(x, Wq, Wk, Wv, qkv);

  dim3 ga(SDIM / 64, BB);
  attn_kernel<<<ga, dim3(256), 0, stream>>>(qkv, out);
}

// Round 4
// 264.591 us; speedup vs baseline: 10.7957x; 1.6429x over previous
//
#include <hip/hip_runtime.h>
#include <math.h>

#define SDIM 4096
#define DIN  1024
#define DOUT 64
#define BB   4
#define MTOT (BB * SDIM)   // 16384 rows

typedef __attribute__((ext_vector_type(8))) short short8;   // 8 x bf16
typedef __attribute__((ext_vector_type(4))) float floatx4;

static __device__ __forceinline__ unsigned short f2bf(float f) {
  union { float f; unsigned int u; } v; v.f = f;
  unsigned int r = v.u + 0x7fffu + ((v.u >> 16) & 1u);
  return (unsigned short)(r >> 16);
}

static __device__ __forceinline__ floatx4 mfma16(short8 a, short8 b, floatx4 c) {
  return __builtin_amdgcn_mfma_f32_16x16x32_bf16(a, b, c, 0, 0, 0);
}

// ---------------------------------------------------------------------------
// W -> bf16:  wb[o][k], o<64: 0.125*Wq ; 64..127: Wk ; 128..191: Wv
// ---------------------------------------------------------------------------
__global__ __launch_bounds__(256) void wcvt_kernel(
    const float* __restrict__ Wq, const float* __restrict__ Wk,
    const float* __restrict__ Wv, unsigned short* __restrict__ wb) {
  const int idx  = blockIdx.x * 256 + threadIdx.x;
  const int flat = idx * 4;
  const int m    = flat >> 16;            // which matrix (65536 elems each)
  const int off  = flat & 65535;
  const float* src = (m == 0) ? Wq : (m == 1) ? Wk : Wv;
  const float  s   = (m == 0) ? 0.125f : 1.0f;
  float4 v = *(const float4*)(src + off);
  ushort4 u;
  u.x = f2bf(v.x * s); u.y = f2bf(v.y * s);
  u.z = f2bf(v.z * s); u.w = f2bf(v.w * s);
  *(ushort4*)(wb + (size_t)m * 65536 + off) = u;
}

// ---------------------------------------------------------------------------
// Projection, bf16 MFMA: out = x(16384x1024) @ wb^T(1024x192).
// grid = 256 blocks (64-row M-tiles), block = 256 (4 waves, 2x2 partition).
// x staged f32->bf16 in LDS (stride 72 shorts). W B-frags straight from L2.
// Epilogue: q,k row-major bf16; v transposed via LDS into vt[b][d][s].
// ---------------------------------------------------------------------------
__global__ __launch_bounds__(256) void proj_kernel(
    const float* __restrict__ x, const unsigned short* __restrict__ wb,
    unsigned short* __restrict__ qk, unsigned short* __restrict__ vt) {
  __shared__ short Xs[64][72];
  __shared__ short Vl[64][72];

  const int tid  = threadIdx.x;
  const int wave = tid >> 6;
  const int lane = tid & 63;
  const int quad = lane >> 4;
  const int l16  = lane & 15;
  const int rw   = wave & 1;    // row half (32 rows)
  const int cw   = wave >> 1;   // col half (96 cols = 6 frags)
  const int row0 = blockIdx.x * 64;

  floatx4 acc[2][6];
#pragma unroll
  for (int i = 0; i < 2; i++)
#pragma unroll
    for (int j = 0; j < 6; j++) acc[i][j] = floatx4{0, 0, 0, 0};

  const int sr = tid >> 2;          // staging row 0..63
  const int sc = (tid & 3) * 16;    // staging col {0,16,32,48}

  for (int k0 = 0; k0 < DIN; k0 += 64) {
    __syncthreads();
    {
      const float* xp = x + (size_t)(row0 + sr) * DIN + k0 + sc;
      float4 a0 = *(const float4*)(xp);
      float4 a1 = *(const float4*)(xp + 4);
      float4 a2 = *(const float4*)(xp + 8);
      float4 a3 = *(const float4*)(xp + 12);
      short8 s0, s1;
      s0[0]=f2bf(a0.x); s0[1]=f2bf(a0.y); s0[2]=f2bf(a0.z); s0[3]=f2bf(a0.w);
      s0[4]=f2bf(a1.x); s0[5]=f2bf(a1.y); s0[6]=f2bf(a1.z); s0[7]=f2bf(a1.w);
      s1[0]=f2bf(a2.x); s1[1]=f2bf(a2.y); s1[2]=f2bf(a2.z); s1[3]=f2bf(a2.w);
      s1[4]=f2bf(a3.x); s1[5]=f2bf(a3.y); s1[6]=f2bf(a3.z); s1[7]=f2bf(a3.w);
      *(short8*)&Xs[sr][sc]     = s0;
      *(short8*)&Xs[sr][sc + 8] = s1;
    }
    __syncthreads();

#pragma unroll
    for (int h = 0; h < 2; h++) {   // 32-k halves of the 64-k tile
      short8 a0 = *(const short8*)&Xs[rw * 32 + l16][h * 32 + quad * 8];
      short8 a1 = *(const short8*)&Xs[rw * 32 + 16 + l16][h * 32 + quad * 8];
#pragma unroll
      for (int f = 0; f < 6; f++) {
        const int col = (cw * 6 + f) * 16 + l16;
        short8 b = *(const short8*)(wb + (size_t)col * DIN + k0 + h * 32 + quad * 8);
        acc[0][f] = mfma16(a0, b, acc[0][f]);
        acc[1][f] = mfma16(a1, b, acc[1][f]);
      }
    }
  }

  // epilogue: C-layout frag (row = quad*4+r, col = f*16+l16)
#pragma unroll
  for (int rr = 0; rr < 2; rr++)
#pragma unroll
    for (int f = 0; f < 6; f++) {
      const int col = (cw * 6 + f) * 16 + l16;
      const int lrow = rw * 32 + rr * 16 + quad * 4;   // + r
      if (col < 64) {
#pragma unroll
        for (int r = 0; r < 4; r++)
          qk[(size_t)(row0 + lrow + r) * 64 + col] = f2bf(acc[rr][f][r]);
      } else if (col < 128) {
#pragma unroll
        for (int r = 0; r < 4; r++)
          qk[(size_t)MTOT * 64 + (size_t)(row0 + lrow + r) * 64 + (col - 64)] =
              f2bf(acc[rr][f][r]);
      } else {
        const int d = col - 128;
#pragma unroll
        for (int r = 0; r < 4; r++)
          Vl[d][lrow + r] = (short)f2bf(acc[rr][f][r]);
      }
    }
  __syncthreads();

  // cooperative coalesced store of V^T tile: vt[b][d][s]
  {
    const int d  = tid >> 2;
    const int j  = (tid & 3) * 16;
    const int bb = row0 >> 12;       // batch
    const int sb = row0 & 4095;      // seq offset within batch
    unsigned short* dst = vt + ((size_t)bb * 64 + d) * SDIM + sb + j;
    *(short8*)(dst)     = *(const short8*)&Vl[d][j];
    *(short8*)(dst + 8) = *(const short8*)&Vl[d][j + 8];
  }
}

// ---------------------------------------------------------------------------
// Flash attention, wave-autonomous, key-split (flash-decoding style).
// Task = (b, qt, c): 16 query rows x key-chunk. K, V^T frags from L2.
// ---------------------------------------------------------------------------
__global__ __launch_bounds__(256) void attn_kernel(
    const unsigned short* __restrict__ qk, const unsigned short* __restrict__ vt,
    float* __restrict__ po, float* __restrict__ pml, int C, int chunk_keys) {
  __shared__ __align__(16) short Pl[4][16 * 72];

  const int tid  = threadIdx.x;
  const int wave = tid >> 6;
  const int lane = tid & 63;
  const int quad = lane >> 4;
  const int l16  = lane & 15;

  const int wg = blockIdx.x * 4 + wave;
  const int c   = wg % C;
  const int rem = wg / C;
  const int qt  = rem & 255;
  const int b   = rem >> 8;

  const int q_end   = qt * 16 + 15;
  const int k_start = c * chunk_keys;
  if (k_start > q_end) return;                    // inactive task
  const int k_lim = min(k_start + chunk_keys, q_end + 1);

  const unsigned short* qs = qk;
  const unsigned short* ks = qk + (size_t)MTOT * 64;

  const unsigned short* qrow = qs + (size_t)(b * SDIM + qt * 16 + l16) * 64;
  const short8 aq0 = *(const short8*)(qrow + quad * 8);
  const short8 aq1 = *(const short8*)(qrow + 32 + quad * 8);

  float m[4]  = {-INFINITY, -INFINITY, -INFINITY, -INFINITY};
  float lw[4] = {0.f, 0.f, 0.f, 0.f};
  floatx4 o[4] = {floatx4{0,0,0,0}, floatx4{0,0,0,0},
                  floatx4{0,0,0,0}, floatx4{0,0,0,0}};
  short* Pw = &Pl[wave][0];

  for (int k0 = k_start; k0 < k_lim; k0 += 64) {
    // ---- S = Q K^T ----
    floatx4 sa[4] = {floatx4{0,0,0,0}, floatx4{0,0,0,0},
                     floatx4{0,0,0,0}, floatx4{0,0,0,0}};
#pragma unroll
    for (int f = 0; f < 4; f++) {
      const unsigned short* kp =
          ks + (size_t)(b * SDIM + k0 + f * 16 + l16) * 64 + quad * 8;
      const short8 bk0 = *(const short8*)(kp);
      const short8 bk1 = *(const short8*)(kp + 32);
      sa[f] = mfma16(aq0, bk0, sa[f]);
      sa[f] = mfma16(aq1, bk1, sa[f]);
    }

    // Causal mask. NOTE: must trigger whenever the tile's max key reaches the
    // tile's MINIMUM row (qt*16), not q_end — with 16-row q-tiles the key
    // tile can end exactly at q_end (qt ≡ 3 mod 4) and still cover future
    // keys for rows < q_end. (R3 bug: `k0+63 > q_end` missed that case.)
    if (k0 + 63 >= qt * 16) {
#pragma unroll
      for (int f = 0; f < 4; f++) {
        const int key = k0 + f * 16 + l16;
#pragma unroll
        for (int r = 0; r < 4; r++)
          if (key > qt * 16 + quad * 4 + r) sa[f][r] = -INFINITY;
      }
    }

    // ---- online softmax (row = quad*4 + r; reduce over l16 within quad) ----
    float mx[4], al[4], rs[4];
#pragma unroll
    for (int r = 0; r < 4; r++)
      mx[r] = fmaxf(fmaxf(sa[0][r], sa[1][r]), fmaxf(sa[2][r], sa[3][r]));
#pragma unroll
    for (int off = 1; off < 16; off <<= 1)
#pragma unroll
      for (int r = 0; r < 4; r++)
        mx[r] = fmaxf(mx[r], __shfl_xor(mx[r], off));
#pragma unroll
    for (int r = 0; r < 4; r++) {
      const float nm  = fmaxf(m[r], mx[r]);
      const float nme = (nm == -INFINITY) ? 0.f : nm;   // fully-masked-row guard
      al[r] = __expf(m[r] - nme);
      m[r]  = nm;
#pragma unroll
      for (int f = 0; f < 4; f++) sa[f][r] = __expf(sa[f][r] - nme);
    }
#pragma unroll
    for (int r = 0; r < 4; r++)
      rs[r] = (sa[0][r] + sa[1][r]) + (sa[2][r] + sa[3][r]);
#pragma unroll
    for (int off = 1; off < 16; off <<= 1)
#pragma unroll
      for (int r = 0; r < 4; r++)
        rs[r] += __shfl_xor(rs[r], off);
#pragma unroll
    for (int r = 0; r < 4; r++) lw[r] = lw[r] * al[r] + rs[r];
#pragma unroll
    for (int f = 0; f < 4; f++)
#pragma unroll
      for (int r = 0; r < 4; r++) o[f][r] *= al[r];

    // ---- P: C-layout -> A-layout via wave-private LDS (no barrier) ----
#pragma unroll
    for (int f = 0; f < 4; f++)
#pragma unroll
      for (int r = 0; r < 4; r++)
        Pw[(quad * 4 + r) * 72 + f * 16 + l16] = (short)f2bf(sa[f][r]);
    const short8 ap0 = *(const short8*)&Pw[l16 * 72 + quad * 8];
    const short8 ap1 = *(const short8*)&Pw[l16 * 72 + 32 + quad * 8];

    // ---- O += P V  (B-frags from vt = V^T, contiguous in key) ----
#pragma unroll
    for (int f = 0; f < 4; f++) {
      const unsigned short* vp =
          vt + ((size_t)b * 64 + f * 16 + l16) * SDIM + k0 + quad * 8;
      const short8 bv0 = *(const short8*)(vp);
      const short8 bv1 = *(const short8*)(vp + 32);
      o[f] = mfma16(ap0, bv0, o[f]);
      o[f] = mfma16(ap1, bv1, o[f]);
    }
  }

  // ---- write partial (m, l, O) ----
  const size_t task = ((size_t)(b * 256 + qt)) * C + c;
  float* pot = po + task * 1024;
#pragma unroll
  for (int f = 0; f < 4; f++)
#pragma unroll
    for (int r = 0; r < 4; r++)
      pot[(quad * 4 + r) * 64 + f * 16 + l16] = o[f][r];
  if (l16 == 0) {
    float* pm = pml + task * 64;
#pragma unroll
    for (int r = 0; r < 4; r++) {
      pm[quad * 4 + r]      = m[r];
      pm[32 + quad * 4 + r] = lw[r];
    }
  }
}

// ---------------------------------------------------------------------------
// Merge partials: out[row][col] = sum_c O_c e^{m_c-M} / sum_c l_c e^{m_c-M}
// ---------------------------------------------------------------------------
__global__ __launch_bounds__(256) void merge_kernel(
    const float* __restrict__ po, const float* __restrict__ pml,
    float* __restrict__ out, int C, int chunk_keys) {
  const int bq = blockIdx.x;
  const int qt = bq & 255;
  const int b  = bq >> 8;
  const int q_end = qt * 16 + 15;
  const int nc = min(q_end / chunk_keys + 1, C);

  __shared__ float sm[8][16];
  __shared__ float sl[8][16];
  const int tid = threadIdx.x;
  if (tid < nc * 16) {
    const int cc = tid >> 4, rr = tid & 15;
    const size_t task = (size_t)bq * C + cc;
    sm[cc][rr] = pml[task * 64 + rr];
    sl[cc][rr] = pml[task * 64 + 32 + rr];
  }
  __syncthreads();

  const int col = tid & 63;
  const int r0  = tid >> 6;
#pragma unroll
  for (int i = 0; i < 4; i++) {
    const int row = r0 * 4 + i;
    float M = -INFINITY;
    for (int cc = 0; cc < nc; cc++) M = fmaxf(M, sm[cc][row]);
    float L = 0.f, O = 0.f;
    for (int cc = 0; cc < nc; cc++) {
      const float al = __expf(sm[cc][row] - M);
      L += sl[cc][row] * al;
      O += po[((size_t)bq * C + cc) * 1024 + row * 64 + col] * al;
    }
    out[((size_t)b * SDIM + qt * 16 + row) * 64 + col] = O / L;
  }
}

extern "C" void kernel_launch(void* const* d_in, const int* in_sizes, int n_in,
                              void* d_out, int out_size, void* d_ws, size_t ws_size,
                              hipStream_t stream) {
  const float* x  = (const float*)d_in[0];
  const float* Wq = (const float*)d_in[1];
  const float* Wk = (const float*)d_in[2];
  const float* Wv = (const float*)d_in[3];
  float* out = (float*)d_out;

  // ws layout: qk (4 MB) | vt (2 MB) | wb (384 KB, pad to 512 KB) | po | pml
  unsigned short* qk = (unsigned short*)d_ws;
  unsigned short* vt = qk + (size_t)2 * MTOT * 64;
  unsigned short* wb = vt + (size_t)BB * 64 * SDIM;
  const size_t po_off = 6 * 1024 * 1024 + 512 * 1024;
  float* po = (float*)((char*)d_ws + po_off);

  int C = 1;
  for (int c = 8; c >= 1; c >>= 1) {
    const size_t need = po_off + (size_t)1024 * c * 1024 * 4   // po
                      + (size_t)1024 * c * 64 * 4;             // pml
    if (need <= ws_size) { C = c; break; }
  }
  float* pml = po + (size_t)1024 * C * 1024;
  const int chunk_keys = SDIM / C;

  wcvt_kernel<<<dim3(192), dim3(256), 0, stream>>>(Wq, Wk, Wv, wb);
  proj_kernel<<<dim3(MTOT / 64), dim3(256), 0, stream>>>(x, wb, qk, vt);
  attn_kernel<<<dim3(256 * C), dim3(256), 0, stream>>>(qk, vt, po, pml, C, chunk_keys);
  merge_kernel<<<dim3(1024), dim3(256), 0, stream>>>(po, pml, out, C, chunk_keys);
}

// Round 5
// 184.361 us; speedup vs baseline: 15.4937x; 1.4352x over previous
//
#include <hip/hip_runtime.h>
#include <math.h>

#define SDIM 4096
#define DIN  1024
#define DOUT 64
#define BB   4
#define MTOT (BB * SDIM)   // 16384 rows

typedef __attribute__((ext_vector_type(8))) short short8;   // 8 x bf16
typedef __attribute__((ext_vector_type(4))) float floatx4;

static __device__ __forceinline__ unsigned short f2bf(float f) {
  union { float f; unsigned int u; } v; v.f = f;
  unsigned int r = v.u + 0x7fffu + ((v.u >> 16) & 1u);
  return (unsigned short)(r >> 16);
}

static __device__ __forceinline__ floatx4 mfma16(short8 a, short8 b, floatx4 c) {
  return __builtin_amdgcn_mfma_f32_16x16x32_bf16(a, b, c, 0, 0, 0);
}

// DPP lane-permute within each 16-lane row (our softmax-reduction domain:
// lanes quad*16 + l16). Sequence xor1,xor2,half_mirror,mirror reduces all 16.
template <int CTRL>
static __device__ __forceinline__ float dpp_mov(float x) {
  union { float f; int i; } u; u.f = x;
  u.i = __builtin_amdgcn_update_dpp(u.i, u.i, CTRL, 0xF, 0xF, true);
  return u.f;
}
static __device__ __forceinline__ void red16_max(float v[4]) {
#pragma unroll
  for (int r = 0; r < 4; r++) v[r] = fmaxf(v[r], dpp_mov<0x0B1>(v[r]));
#pragma unroll
  for (int r = 0; r < 4; r++) v[r] = fmaxf(v[r], dpp_mov<0x04E>(v[r]));
#pragma unroll
  for (int r = 0; r < 4; r++) v[r] = fmaxf(v[r], dpp_mov<0x141>(v[r]));
#pragma unroll
  for (int r = 0; r < 4; r++) v[r] = fmaxf(v[r], dpp_mov<0x140>(v[r]));
}
static __device__ __forceinline__ void red16_sum(float v[4]) {
#pragma unroll
  for (int r = 0; r < 4; r++) v[r] += dpp_mov<0x0B1>(v[r]);
#pragma unroll
  for (int r = 0; r < 4; r++) v[r] += dpp_mov<0x04E>(v[r]);
#pragma unroll
  for (int r = 0; r < 4; r++) v[r] += dpp_mov<0x141>(v[r]);
#pragma unroll
  for (int r = 0; r < 4; r++) v[r] += dpp_mov<0x140>(v[r]);
}

// ---------------------------------------------------------------------------
// W -> bf16:  wb[o][k], o<64: 0.125*Wq ; 64..127: Wk ; 128..191: Wv
// ---------------------------------------------------------------------------
__global__ __launch_bounds__(256) void wcvt_kernel(
    const float* __restrict__ Wq, const float* __restrict__ Wk,
    const float* __restrict__ Wv, unsigned short* __restrict__ wb) {
  const int idx  = blockIdx.x * 256 + threadIdx.x;
  const int flat = idx * 4;
  const int m    = flat >> 16;
  const int off  = flat & 65535;
  const float* src = (m == 0) ? Wq : (m == 1) ? Wk : Wv;
  const float  s   = (m == 0) ? 0.125f : 1.0f;
  float4 v = *(const float4*)(src + off);
  ushort4 u;
  u.x = f2bf(v.x * s); u.y = f2bf(v.y * s);
  u.z = f2bf(v.z * s); u.w = f2bf(v.w * s);
  *(ushort4*)(wb + (size_t)m * 65536 + off) = u;
}

// ---------------------------------------------------------------------------
// Projection, bf16 MFMA: out = x(16384x1024) @ wb^T(1024x192).
// 512 blocks of 32-row M-tiles (2 blocks/CU for latency hiding; R4 had 256
// blocks = 1 wave/SIMD, latency-bound). 4 waves: wave w owns cols w*48..w*48+47
// (3 frags), all 32 rows. x staged f32->bf16 in LDS (stride 72 shorts).
// Epilogue: q,k row-major bf16; v transposed via LDS into vt[b][d][s].
// ---------------------------------------------------------------------------
__global__ __launch_bounds__(256) void proj_kernel(
    const float* __restrict__ x, const unsigned short* __restrict__ wb,
    unsigned short* __restrict__ qk, unsigned short* __restrict__ vt) {
  __shared__ short Xs[32][72];
  __shared__ short Vl[64][36];

  const int tid  = threadIdx.x;
  const int wave = tid >> 6;
  const int lane = tid & 63;
  const int quad = lane >> 4;
  const int l16  = lane & 15;
  const int row0 = blockIdx.x * 32;

  floatx4 acc[2][3];
#pragma unroll
  for (int i = 0; i < 2; i++)
#pragma unroll
    for (int j = 0; j < 3; j++) acc[i][j] = floatx4{0, 0, 0, 0};

  const int sr = tid >> 3;          // staging row 0..31
  const int sc = (tid & 7) * 8;     // staging col {0,8,...,56}

  for (int k0 = 0; k0 < DIN; k0 += 64) {
    const float* xp = x + (size_t)(row0 + sr) * DIN + k0 + sc;
    float4 a0 = *(const float4*)(xp);
    float4 a1 = *(const float4*)(xp + 4);
    __syncthreads();
    short8 s0;
    s0[0]=f2bf(a0.x); s0[1]=f2bf(a0.y); s0[2]=f2bf(a0.z); s0[3]=f2bf(a0.w);
    s0[4]=f2bf(a1.x); s0[5]=f2bf(a1.y); s0[6]=f2bf(a1.z); s0[7]=f2bf(a1.w);
    *(short8*)&Xs[sr][sc] = s0;
    __syncthreads();

#pragma unroll
    for (int h = 0; h < 2; h++) {   // 32-k halves
      short8 aa0 = *(const short8*)&Xs[l16][h * 32 + quad * 8];
      short8 aa1 = *(const short8*)&Xs[16 + l16][h * 32 + quad * 8];
#pragma unroll
      for (int f = 0; f < 3; f++) {
        const int col = (wave * 3 + f) * 16 + l16;
        short8 b = *(const short8*)(wb + (size_t)col * DIN + k0 + h * 32 + quad * 8);
        acc[0][f] = mfma16(aa0, b, acc[0][f]);
        acc[1][f] = mfma16(aa1, b, acc[1][f]);
      }
    }
  }

  // epilogue: C-layout frag (row = quad*4+r, col = f*16+l16)
#pragma unroll
  for (int rr = 0; rr < 2; rr++)
#pragma unroll
    for (int f = 0; f < 3; f++) {
      const int col  = (wave * 3 + f) * 16 + l16;
      const int lrow = rr * 16 + quad * 4;   // + r
      if (col < 64) {
#pragma unroll
        for (int r = 0; r < 4; r++)
          qk[(size_t)(row0 + lrow + r) * 64 + col] = f2bf(acc[rr][f][r]);
      } else if (col < 128) {
#pragma unroll
        for (int r = 0; r < 4; r++)
          qk[(size_t)MTOT * 64 + (size_t)(row0 + lrow + r) * 64 + (col - 64)] =
              f2bf(acc[rr][f][r]);
      } else {
        const int d = col - 128;
#pragma unroll
        for (int r = 0; r < 4; r++)
          Vl[d][lrow + r] = (short)f2bf(acc[rr][f][r]);
      }
    }
  __syncthreads();

  // cooperative coalesced store of V^T tile: vt[b][d][s], 32-seq chunk
  {
    const int d  = tid >> 2;
    const int j  = (tid & 3) * 8;
    const int bb = row0 >> 12;       // batch
    const int sb = row0 & 4095;      // seq offset within batch
    unsigned short* dst = vt + ((size_t)bb * 64 + d) * SDIM + sb + j;
    *(short8*)(dst) = *(const short8*)&Vl[d][j];
  }
}

// ---------------------------------------------------------------------------
// Flash attention v2: block = (b, 64-row q-block, key-chunk). 4 waves share
// LDS-staged K and V^T tiles (4x global-traffic cut vs R4's per-wave loads;
// loads issued before the barrier to overlap latency). Wave w owns q rows
// qb*64+16w..+15. Softmax reductions via DPP (in-row 16-lane: xor1,xor2,
// half_mirror,mirror) instead of ds-pipe shuffles. P reuses the K-tile LDS
// (wave-private 16-row region; post-QK barrier makes that safe).
// ---------------------------------------------------------------------------
__global__ __launch_bounds__(256) void attn_kernel(
    const unsigned short* __restrict__ qk, const unsigned short* __restrict__ vt,
    float* __restrict__ po, float* __restrict__ pml, int C, int chunk_keys) {
  __shared__ __align__(16) short Kl[64 * 72];
  __shared__ __align__(16) short Vt[64 * 72];

  const int tid  = threadIdx.x;
  const int wave = tid >> 6;
  const int lane = tid & 63;
  const int quad = lane >> 4;
  const int l16  = lane & 15;

  const int bx  = blockIdx.x;
  const int c   = bx % C;
  const int rem = bx / C;
  const int qb  = rem & 63;          // 64-row q-block
  const int b   = rem >> 6;

  const int k_start = c * chunk_keys;
  if (k_start > qb * 64 + 63) return;                 // inactive block
  const int k_lim = min(k_start + chunk_keys, qb * 64 + 64);  // block-uniform

  const int qt  = qb * 4 + wave;     // 16-row tile index (partials/task id)
  const int wq0 = qt * 16;           // wave's first q row

  const unsigned short* qs = qk;
  const unsigned short* ks = qk + (size_t)MTOT * 64;

  const unsigned short* qrow = qs + (size_t)(b * SDIM + wq0 + l16) * 64;
  const short8 aq0 = *(const short8*)(qrow + quad * 8);
  const short8 aq1 = *(const short8*)(qrow + 32 + quad * 8);

  float m[4]  = {-INFINITY, -INFINITY, -INFINITY, -INFINITY};
  float lw[4] = {0.f, 0.f, 0.f, 0.f};
  floatx4 o[4] = {floatx4{0,0,0,0}, floatx4{0,0,0,0},
                  floatx4{0,0,0,0}, floatx4{0,0,0,0}};

  // staging coords: thread handles 32 B (2 x short8) of one row of each tile
  const int sr = tid >> 2;          // 0..63
  const int sc = (tid & 3) * 16;    // {0,16,32,48}
  const unsigned short* kgp = ks + (size_t)(b * SDIM + k_start + sr) * 64 + sc;
  const unsigned short* vgp = vt + ((size_t)b * 64 + sr) * SDIM + k_start + sc;

  for (int k0 = k_start; k0 < k_lim; k0 += 64) {
    // issue staging loads before the barrier (latency overlaps barrier wait)
    const short8 kk0 = *(const short8*)(kgp);
    const short8 kk1 = *(const short8*)(kgp + 8);
    const short8 vv0 = *(const short8*)(vgp);
    const short8 vv1 = *(const short8*)(vgp + 8);
    kgp += 64 * 64;
    vgp += 64;
    __syncthreads();   // previous tile's P/V reads complete before overwrite
    *(short8*)&Kl[sr * 72 + sc]      = kk0;
    *(short8*)&Kl[sr * 72 + sc + 8]  = kk1;
    *(short8*)&Vt[sr * 72 + sc]      = vv0;
    *(short8*)&Vt[sr * 72 + sc + 8]  = vv1;
    __syncthreads();

    // ---- S = Q K^T ----
    floatx4 sa[4] = {floatx4{0,0,0,0}, floatx4{0,0,0,0},
                     floatx4{0,0,0,0}, floatx4{0,0,0,0}};
#pragma unroll
    for (int f = 0; f < 4; f++) {
      const short8 bk0 = *(const short8*)&Kl[(f * 16 + l16) * 72 + quad * 8];
      const short8 bk1 = *(const short8*)&Kl[(f * 16 + l16) * 72 + 32 + quad * 8];
      sa[f] = mfma16(aq0, bk0, sa[f]);
      sa[f] = mfma16(aq1, bk1, sa[f]);
    }
    __syncthreads();   // all waves' K-frag reads done -> P may overwrite Kl

    // causal mask: trigger when tile's max key reaches wave's MIN row (wq0)
    if (k0 + 63 >= wq0) {
#pragma unroll
      for (int f = 0; f < 4; f++) {
        const int key = k0 + f * 16 + l16;
#pragma unroll
        for (int r = 0; r < 4; r++)
          if (key > wq0 + quad * 4 + r) sa[f][r] = -INFINITY;
      }
    }

    // ---- online softmax (row = quad*4+r; reduce over l16 via DPP) ----
    float mx[4], al[4], rs[4];
#pragma unroll
    for (int r = 0; r < 4; r++)
      mx[r] = fmaxf(fmaxf(sa[0][r], sa[1][r]), fmaxf(sa[2][r], sa[3][r]));
    red16_max(mx);
#pragma unroll
    for (int r = 0; r < 4; r++) {
      const float nm  = fmaxf(m[r], mx[r]);
      const float nme = (nm == -INFINITY) ? 0.f : nm;   // fully-masked guard
      al[r] = __expf(m[r] - nme);
      m[r]  = nm;
#pragma unroll
      for (int f = 0; f < 4; f++) sa[f][r] = __expf(sa[f][r] - nme);
    }
#pragma unroll
    for (int r = 0; r < 4; r++)
      rs[r] = (sa[0][r] + sa[1][r]) + (sa[2][r] + sa[3][r]);
    red16_sum(rs);
#pragma unroll
    for (int r = 0; r < 4; r++) lw[r] = lw[r] * al[r] + rs[r];
#pragma unroll
    for (int f = 0; f < 4; f++)
#pragma unroll
      for (int r = 0; r < 4; r++) o[f][r] *= al[r];

    // ---- P -> wave-private rows of Kl (C-layout -> A-layout) ----
#pragma unroll
    for (int f = 0; f < 4; f++)
#pragma unroll
      for (int r = 0; r < 4; r++) {
        union { float f; unsigned int u; } pv; pv.f = sa[f][r];
        Kl[(wave * 16 + quad * 4 + r) * 72 + f * 16 + l16] =
            (short)((pv.u + 0x8000u) >> 16);   // round-half-up to bf16
      }
    const short8 ap0 = *(const short8*)&Kl[(wave * 16 + l16) * 72 + quad * 8];
    const short8 ap1 = *(const short8*)&Kl[(wave * 16 + l16) * 72 + 32 + quad * 8];

    // ---- O += P V ----
#pragma unroll
    for (int f = 0; f < 4; f++) {
      const short8 bv0 = *(const short8*)&Vt[(f * 16 + l16) * 72 + quad * 8];
      const short8 bv1 = *(const short8*)&Vt[(f * 16 + l16) * 72 + 32 + quad * 8];
      o[f] = mfma16(ap0, bv0, o[f]);
      o[f] = mfma16(ap1, bv1, o[f]);
    }
  }

  // ---- write partial (m, l, O) ----
  const size_t task = ((size_t)(b * 256 + qt)) * C + c;
  float* pot = po + task * 1024;
#pragma unroll
  for (int f = 0; f < 4; f++)
#pragma unroll
    for (int r = 0; r < 4; r++)
      pot[(quad * 4 + r) * 64 + f * 16 + l16] = o[f][r];
  if (l16 == 0) {
    float* pm = pml + task * 64;
#pragma unroll
    for (int r = 0; r < 4; r++) {
      pm[quad * 4 + r]      = m[r];
      pm[32 + quad * 4 + r] = lw[r];
    }
  }
}

// ---------------------------------------------------------------------------
// Merge partials: out[row][col] = sum_c O_c e^{m_c-M} / sum_c l_c e^{m_c-M}
// ---------------------------------------------------------------------------
__global__ __launch_bounds__(256) void merge_kernel(
    const float* __restrict__ po, const float* __restrict__ pml,
    float* __restrict__ out, int C, int chunk_keys) {
  const int bq = blockIdx.x;
  const int qt = bq & 255;
  const int b  = bq >> 8;
  const int q_end = qt * 16 + 15;
  const int nc = min(q_end / chunk_keys + 1, C);

  __shared__ float sm[8][16];
  __shared__ float sl[8][16];
  const int tid = threadIdx.x;
  if (tid < nc * 16) {
    const int cc = tid >> 4, rr = tid & 15;
    const size_t task = (size_t)bq * C + cc;
    sm[cc][rr] = pml[task * 64 + rr];
    sl[cc][rr] = pml[task * 64 + 32 + rr];
  }
  __syncthreads();

  const int col = tid & 63;
  const int r0  = tid >> 6;
#pragma unroll
  for (int i = 0; i < 4; i++) {
    const int row = r0 * 4 + i;
    float M = -INFINITY;
    for (int cc = 0; cc < nc; cc++) M = fmaxf(M, sm[cc][row]);
    float L = 0.f, O = 0.f;
    for (int cc = 0; cc < nc; cc++) {
      const float al = __expf(sm[cc][row] - M);
      L += sl[cc][row] * al;
      O += po[((size_t)bq * C + cc) * 1024 + row * 64 + col] * al;
    }
    out[((size_t)b * SDIM + qt * 16 + row) * 64 + col] = O / L;
  }
}

extern "C" void kernel_launch(void* const* d_in, const int* in_sizes, int n_in,
                              void* d_out, int out_size, void* d_ws, size_t ws_size,
                              hipStream_t stream) {
  const float* x  = (const float*)d_in[0];
  const float* Wq = (const float*)d_in[1];
  const float* Wk = (const float*)d_in[2];
  const float* Wv = (const float*)d_in[3];
  float* out = (float*)d_out;

  // ws layout: qk (4 MB) | vt (2 MB) | wb (384 KB, pad to 512 KB) | po | pml
  unsigned short* qk = (unsigned short*)d_ws;
  unsigned short* vt = qk + (size_t)2 * MTOT * 64;
  unsigned short* wb = vt + (size_t)BB * 64 * SDIM;
  const size_t po_off = 6 * 1024 * 1024 + 512 * 1024;
  float* po = (float*)((char*)d_ws + po_off);

  int C = 1;
  for (int c = 8; c >= 1; c >>= 1) {
    const size_t need = po_off + (size_t)1024 * c * 1024 * 4   // po
                      + (size_t)1024 * c * 64 * 4;             // pml
    if (need <= ws_size) { C = c; break; }
  }
  float* pml = po + (size_t)1024 * C * 1024;
  const int chunk_keys = SDIM / C;

  wcvt_kernel<<<dim3(192), dim3(256), 0, stream>>>(Wq, Wk, Wv, wb);
  proj_kernel<<<dim3(MTOT / 32), dim3(256), 0, stream>>>(x, wb, qk, vt);
  attn_kernel<<<dim3(256 * C), dim3(256), 0, stream>>>(qk, vt, po, pml, C, chunk_keys);
  merge_kernel<<<dim3(1024), dim3(256), 0, stream>>>(po, pml, out, C, chunk_keys);
}